// Round 8
// baseline (144.924 us; speedup 1.0000x reference)
//
#include <hip/hip_runtime.h>
#include <hip/hip_cooperative_groups.h>

namespace cg = cooperative_groups;

#define NB   2
#define SKV  1024
#define NSQ  512
#define HIN  256
#define HA   128

// projections pre-scaled by 2*log2(e):  exp2(KSC*x) = e^{2x}
// tanh(x) = 1 - 2/(e^{2x}+1); softmax is shift-invariant so the constant
// W0+bv terms of the score are dropped entirely.
#define KSC   2.8853900817779268f   // 2*log2(e)

// ---------------- single cooperative kernel ----------------
// grid 256 x 1024 (1 block/CU, co-resident).
// stage A: block bid projects kv rows [bid*8, bid*8+8) -> ekT (global,
//          interleaved ekT[b][a>>2][s][a&3]) and its OWN 4 q rows -> eq_s
//          (LDS only — q-projection never touches global memory).
// grid.sync(): makes ekT visible across XCDs.
// stage B: R6's measured-best fused attn (scores + softmax + weights + out).
__global__ __launch_bounds__(1024) void fused_kernel(
    const float* __restrict__ kv,          // (2048,256)
    const float* __restrict__ qy,          // (1024,256)
    const float* __restrict__ Wkv,         // (256,128)
    const float* __restrict__ bkv,         // (128)
    const float* __restrict__ Wq,          // (256,128)
    const float* __restrict__ bqv,         // (128)
    const float* __restrict__ wv,          // (128)
    float* __restrict__ ekT,               // ws: (b,32,1024,4) interleaved exps
    float* __restrict__ out)               // [262144 out0][1048576 weights]
{
    __shared__ __align__(16) float rowf[8][HIN];       // 8 KB kv-row stage
    __shared__ __align__(16) float qrow[4][HIN];       // 4 KB q-row stage
    __shared__ __align__(16) float eq_s[4][HA];        // 2 KB
    __shared__ __align__(16) float wv_s[HA];           // 0.5 KB
    __shared__ __align__(16) float wt_s[SKV][4];       // 16 KB
    __shared__ __align__(16) float part[16][4][HIN];   // 64 KB
    __shared__ float red[2][4][16];

    const int tid  = threadIdx.x;
    const int lane = tid & 63, wid = tid >> 6;
    const int bid  = blockIdx.x;
    const int bq0  = bid * 4;              // this block's 4 q rows
    const int b    = bq0 >> 9;             // batch (blocks 0-127 b=0, 128-255 b=1)

    // ---- stage A load: 8 kv rows + 4 qy rows + wv ----
    {
        const float4* __restrict__ kvsrc = (const float4*)(kv + (size_t)bid * 8 * HIN);
        const float4* __restrict__ qsrc  = (const float4*)(qy + (size_t)bq0 * HIN);
        if (tid < 512)      ((float4*)rowf)[tid]       = kvsrc[tid];
        else if (tid < 768) ((float4*)qrow)[tid - 512] = qsrc[tid - 512];
        else if (tid < 896) wv_s[tid - 768]            = wv[tid - 768];
    }
    __syncthreads();

    // ---- stage A project: slots 0-3 -> kv row pairs, 4-5 -> q row pairs ----
    {
        const int a = tid & 127, slot = tid >> 7;      // slot wave-uniform
        if (slot < 6) {
            const bool isq = (slot >= 4);
            const int  ra  = isq ? (slot - 4) * 2 : slot * 2;
            const float4* __restrict__ r0p =
                (const float4*)(isq ? qrow[ra] : rowf[ra]);
            const float4* __restrict__ r1p =
                (const float4*)(isq ? qrow[ra + 1] : rowf[ra + 1]);
            const float* __restrict__ W  = isq ? Wq  : Wkv;
            const float* __restrict__ bs = isq ? bqv : bkv;

            float a0 = 0.f, a1 = 0.f;
            #pragma unroll 4
            for (int h4 = 0; h4 < 64; ++h4) {
                const float4 rA = r0p[h4];             // LDS broadcast b128
                const float4 rB = r1p[h4];
                #pragma unroll
                for (int j = 0; j < 4; ++j) {
                    const float w = W[(size_t)(h4 * 4 + j) * HA + a];  // coalesced
                    a0 = fmaf(((const float*)&rA)[j], w, a0);
                    a1 = fmaf(((const float*)&rB)[j], w, a1);
                }
            }
            const float bb = bs[a];
            const float e0 = __builtin_amdgcn_exp2f((a0 + bb) * KSC);
            const float e1 = __builtin_amdgcn_exp2f((a1 + bb) * KSC);
            if (isq) {
                eq_s[ra][a]     = e0;                  // block-local, LDS only
                eq_s[ra + 1][a] = e1;
            } else {
                const int kr0 = bid * 8;               // global kv row base
                const int bI = kr0 >> 10, s0 = kr0 & 1023;
                float* __restrict__ p =
                    ekT + ((size_t)(bI * 32 + (a >> 2)) * SKV + s0) * 4 + (a & 3);
                p[(size_t)ra * 4]       = e0;
                p[(size_t)(ra + 1) * 4] = e1;
            }
        }
    }

    // ---- device-scope: all ekT writes visible to all blocks ----
    cg::this_grid().sync();

    // ---- phase 2: per-thread s, 4 q accumulators; paired rcp over a ----
    const float4* __restrict__ E4 =
        (const float4*)ekT + (size_t)b * 32 * SKV + tid;   // + a4*SKV per iter
    float t0 = 0.f, t1 = 0.f, t2 = 0.f, t3 = 0.f;

    #pragma unroll 4
    for (int a4 = 0; a4 < 32; ++a4) {
        const float4 E = E4[(size_t)a4 * SKV];             // coalesced b128
        const float4 w = ((const float4*)wv_s)[a4];        // LDS broadcast

#define PQ(ACC, QI)                                                           \
        {                                                                     \
            const float4 Q = ((const float4*)eq_s[QI])[a4];  /* broadcast */  \
            float u  = fmaf(E.x, Q.x, 1.f);                                   \
            float v  = fmaf(E.y, Q.y, 1.f);                                   \
            ACC = fmaf(fmaf(w.x, v, w.y * u),                                 \
                       __builtin_amdgcn_rcpf(u * v), ACC);                    \
            float u2 = fmaf(E.z, Q.z, 1.f);                                   \
            float v2 = fmaf(E.w, Q.w, 1.f);                                   \
            ACC = fmaf(fmaf(w.z, v2, w.w * u2),                               \
                       __builtin_amdgcn_rcpf(u2 * v2), ACC);                  \
        }
        PQ(t0, 0) PQ(t1, 1) PQ(t2, 2) PQ(t3, 3)
#undef PQ
    }

    // ---- phase 3: softmax over s.  weight ∝ exp(-2*(t - tmin)) ----
    float tq[4] = {t0, t1, t2, t3};
    #pragma unroll
    for (int q = 0; q < 4; ++q) {
        float m = tq[q];
        #pragma unroll
        for (int o = 32; o > 0; o >>= 1) m = fminf(m, __shfl_down(m, o));
        if (lane == 0) red[0][q][wid] = m;
    }
    __syncthreads();
    float M[4];
    #pragma unroll
    for (int q = 0; q < 4; ++q) {
        float m = red[0][q][0];
        #pragma unroll
        for (int i = 1; i < 16; ++i) m = fminf(m, red[0][q][i]);
        M[q] = m;
    }
    float e[4];
    #pragma unroll
    for (int q = 0; q < 4; ++q) {
        e[q] = __builtin_amdgcn_exp2f((M[q] - tq[q]) * KSC);   // exp(-2(t-tmin))
        float sum = e[q];
        #pragma unroll
        for (int o = 32; o > 0; o >>= 1) sum += __shfl_down(sum, o);
        if (lane == 0) red[1][q][wid] = sum;
    }
    __syncthreads();
    float* __restrict__ outw = out + (size_t)NB * NSQ * HIN;   // weights at 262144
    float wgt[4];
    #pragma unroll
    for (int q = 0; q < 4; ++q) {
        float d = red[1][q][0];
        #pragma unroll
        for (int i = 1; i < 16; ++i) d += red[1][q][i];
        wgt[q] = e[q] * __builtin_amdgcn_rcpf(d);
        outw[(size_t)(bq0 + q) * SKV + tid] = wgt[q];          // coalesced per q
    }
    *(float4*)&wt_s[tid][0] = make_float4(wgt[0], wgt[1], wgt[2], wgt[3]);
    __syncthreads();

    // ---- phase 4: out[q][h] = sum_s w[q][s]*kv[b][s][h] ----
    // wave g handles s in [g*64, g*64+64); lane = float4 chunk of h
    {
        const int g = wid;                 // 0..15
        float4 ac0 = {0,0,0,0}, ac1 = {0,0,0,0}, ac2 = {0,0,0,0}, ac3 = {0,0,0,0};
        const float4* __restrict__ kvb =
            (const float4*)kv + (size_t)(b * SKV + g * 64) * 64;
        #pragma unroll 4
        for (int i = 0; i < 64; ++i) {
            const float4 w4 = *((const float4*)&wt_s[g * 64 + i][0]); // broadcast
            const float4 v  = kvb[(size_t)i * 64 + lane];             // 1KB/wave
            ac0.x = fmaf(w4.x, v.x, ac0.x); ac0.y = fmaf(w4.x, v.y, ac0.y);
            ac0.z = fmaf(w4.x, v.z, ac0.z); ac0.w = fmaf(w4.x, v.w, ac0.w);
            ac1.x = fmaf(w4.y, v.x, ac1.x); ac1.y = fmaf(w4.y, v.y, ac1.y);
            ac1.z = fmaf(w4.y, v.z, ac1.z); ac1.w = fmaf(w4.y, v.w, ac1.w);
            ac2.x = fmaf(w4.z, v.x, ac2.x); ac2.y = fmaf(w4.z, v.y, ac2.y);
            ac2.z = fmaf(w4.z, v.z, ac2.z); ac2.w = fmaf(w4.z, v.w, ac2.w);
            ac3.x = fmaf(w4.w, v.x, ac3.x); ac3.y = fmaf(w4.w, v.y, ac3.y);
            ac3.z = fmaf(w4.w, v.z, ac3.z); ac3.w = fmaf(w4.w, v.w, ac3.w);
        }
        ((float4*)part[g][0])[lane] = ac0;
        ((float4*)part[g][1])[lane] = ac1;
        ((float4*)part[g][2])[lane] = ac2;
        ((float4*)part[g][3])[lane] = ac3;
    }
    __syncthreads();
    {
        const int q = tid >> 8, h = tid & 255;       // 1024 outputs, 1/thread
        float v = 0.f;
        #pragma unroll
        for (int g2 = 0; g2 < 16; ++g2) v += part[g2][q][h];   // stride-1 banks
        out[(size_t)(bq0 + q) * HIN + h] = v;        // coalesced
    }
}

extern "C" void kernel_launch(void* const* d_in, const int* in_sizes, int n_in,
                              void* d_out, int out_size, void* d_ws, size_t ws_size,
                              hipStream_t stream) {
    (void)in_sizes; (void)n_in; (void)out_size; (void)ws_size;
    const float* kv  = (const float*)d_in[0];
    const float* qy  = (const float*)d_in[1];
    const float* Wkv = (const float*)d_in[2];
    const float* bkv = (const float*)d_in[3];
    const float* Wq  = (const float*)d_in[4];
    const float* bqv = (const float*)d_in[5];
    const float* wv  = (const float*)d_in[6];
    float* ekT = (float*)d_ws;                 // 1 MB (eq never hits global)
    float* out = (float*)d_out;

    void* args[] = {
        (void*)&kv, (void*)&qy, (void*)&Wkv, (void*)&bkv,
        (void*)&Wq, (void*)&bqv, (void*)&wv, (void*)&ekT, (void*)&out
    };
    hipLaunchCooperativeKernel(reinterpret_cast<void*>(fused_kernel),
                               dim3(NB * NSQ / 4), dim3(1024), args, 0, stream);
}

// Round 9
// 142.213 us; speedup vs baseline: 1.0191x; 1.0191x over previous
//
#include <hip/hip_runtime.h>

typedef float f32x2 __attribute__((ext_vector_type(2)));

#define NB   2
#define SKV  1024
#define NSQ  512
#define HIN  256
#define HA   128

// projections pre-scaled by 2*log2(e):  exp2(KSC*x) = e^{2x}
// tanh(x) = 1 - 2/(e^{2x}+1); softmax is shift-invariant so the constant
// W0+bv terms of the score are dropped entirely.
#define KSC   2.8853900817779268f   // 2*log2(e)
#define MAGIC 0x1B7F3A29u           // barrier slot token (never a poison pattern)

// ---------------- single fused kernel, NORMAL launch ----------------
// grid 256 x 1024, 97 KB LDS -> exactly 1 block/CU, all 256 co-resident.
// stage A: block bid projects kv rows [bid*8,bid*8+8) -> ekT (global) and its
//          own 4 q rows -> eq_s (LDS only).
// software device barrier (slot-MAGIC, poison-robust, graph-capture safe).
// stage B: R6's fused attn (scores + softmax + weights + out), f32x2-packed.
__global__ __launch_bounds__(1024) void fused_kernel(
    const float* __restrict__ kv,          // (2048,256)
    const float* __restrict__ qy,          // (1024,256)
    const float* __restrict__ Wkv,         // (256,128)
    const float* __restrict__ bkv,         // (128)
    const float* __restrict__ Wq,          // (256,128)
    const float* __restrict__ bqv,         // (128)
    const float* __restrict__ wv,          // (128)
    float* __restrict__ ekT,               // ws: (b,32,1024,4) interleaved exps
    unsigned* __restrict__ slots,          // ws: 256 barrier slots
    float* __restrict__ out)               // [262144 out0][1048576 weights]
{
    __shared__ __align__(16) float rowf[12][HIN];      // 12 KB: 8 kv + 4 q rows
    __shared__ __align__(16) float eq_s[4][HA];        // 2 KB
    __shared__ __align__(16) float wv_s[HA];           // 0.5 KB
    __shared__ __align__(16) float wt_s[SKV][4];       // 16 KB
    __shared__ __align__(16) float part[16][4][HIN];   // 64 KB
    __shared__ float red[2][4][16];

    const int tid  = threadIdx.x;
    const int lane = tid & 63, wid = tid >> 6;
    const int bid  = blockIdx.x;
    const int bq0  = bid * 4;              // this block's 4 q rows
    const int b    = bq0 >> 9;

    // ---- stage A load: 8 kv rows + 4 qy rows + wv ----
    {
        const float4* __restrict__ kvsrc = (const float4*)(kv + (size_t)bid * 8 * HIN);
        const float4* __restrict__ qsrc  = (const float4*)(qy + (size_t)bq0 * HIN);
        if (tid < 512)      ((float4*)rowf)[tid] = kvsrc[tid];
        else if (tid < 768) ((float4*)rowf)[tid] = qsrc[tid - 512];   // rows 8-11
        else if (tid < 896) wv_s[tid - 768]      = wv[tid - 768];
    }
    __syncthreads();

    // ---- stage A project: 16 slots of 64 threads; slot = one row,
    //      thread = channel pair (c, c+1) -> packed FMA ----
    {
        const int slot = wid;              // 0..15 (12-15 idle)
        if (slot < 12) {
            const bool isq = (slot >= 8);
            const int  c   = lane << 1;    // 0,2,..,126
            const float* __restrict__ W   = isq ? Wq  : Wkv;
            const float* __restrict__ bs  = isq ? bqv : bkv;
            const float* __restrict__ row = rowf[slot];

            f32x2 acc = {0.f, 0.f};
            #pragma unroll 4
            for (int h4 = 0; h4 < 64; ++h4) {
                const float4 r4 = ((const float4*)row)[h4];    // LDS broadcast
                #pragma unroll
                for (int j = 0; j < 4; ++j) {
                    const float rv = ((const float*)&r4)[j];
                    const f32x2 w2 = *(const f32x2*)&W[(size_t)(h4 * 4 + j) * HA + c];
                    acc = __builtin_elementwise_fma((f32x2){rv, rv}, w2, acc);
                }
            }
            const f32x2 bb = *(const f32x2*)&bs[c];
            const float e0 = __builtin_amdgcn_exp2f((acc.x + bb.x) * KSC);
            const float e1 = __builtin_amdgcn_exp2f((acc.y + bb.y) * KSC);
            if (isq) {
                eq_s[slot - 8][c]     = e0;        // block-local, LDS only
                eq_s[slot - 8][c + 1] = e1;
            } else {
                const int kr = bid * 8 + slot;     // global kv row
                const int bI = kr >> 10, s0 = kr & 1023;
                float* __restrict__ p =
                    ekT + ((size_t)(bI * 32 + (c >> 2)) * SKV + s0) * 4 + (c & 3);
                p[0] = e0;                         // (c&3) in {0,2}: contiguous
                p[1] = e1;
            }
        }
    }
    __syncthreads();

    // ---- software device barrier (poison-robust, no init required) ----
    if (tid == 0) {
        __threadfence();                   // agent-scope release: ekT visible
        __hip_atomic_store(&slots[bid], MAGIC, __ATOMIC_RELEASE,
                           __HIP_MEMORY_SCOPE_AGENT);
    }
    if (wid == 0) {                        // wave 0 polls all 256 slots
        #pragma unroll
        for (int k = 0; k < 4; ++k) {
            const int i = lane * 4 + k;
            int guard = 0;
            while (__hip_atomic_load(&slots[i], __ATOMIC_ACQUIRE,
                                     __HIP_MEMORY_SCOPE_AGENT) != MAGIC) {
                if (++guard > (1 << 22)) break;        // safety valve
                __builtin_amdgcn_s_sleep(2);
            }
        }
        __threadfence();                   // acquire fence before ekT reads
    }
    __syncthreads();

    // ---- phase 2: per-thread s, 4 q accumulators; packed pair-rcp over a ----
    const float4* __restrict__ E4 =
        (const float4*)ekT + (size_t)b * 32 * SKV + tid;   // + a4*SKV per iter
    const f32x2 one2 = {1.f, 1.f};
    f32x2 t0 = {0,0}, t1 = {0,0}, t2 = {0,0}, t3 = {0,0};

    #pragma unroll 4
    for (int a4 = 0; a4 < 32; ++a4) {
        const float4 E = E4[(size_t)a4 * SKV];             // coalesced b128
        const float4 w = ((const float4*)wv_s)[a4];        // LDS broadcast
        const f32x2 Exy = {E.x, E.y}, Ezw = {E.z, E.w};

#define PQ(ACC, QI)                                                           \
        {                                                                     \
            const float4 Q = ((const float4*)eq_s[QI])[a4];  /* broadcast */  \
            const f32x2 U1 = __builtin_elementwise_fma(Exy,                   \
                                 (f32x2){Q.x, Q.y}, one2);                    \
            const f32x2 U2 = __builtin_elementwise_fma(Ezw,                   \
                                 (f32x2){Q.z, Q.w}, one2);                    \
            f32x2 N, R;                                                       \
            N.x = fmaf(w.x, U1.y, w.y * U1.x);                                \
            N.y = fmaf(w.z, U2.y, w.w * U2.x);                                \
            R.x = __builtin_amdgcn_rcpf(U1.x * U1.y);                         \
            R.y = __builtin_amdgcn_rcpf(U2.x * U2.y);                         \
            ACC = __builtin_elementwise_fma(N, R, ACC);                       \
        }
        PQ(t0, 0) PQ(t1, 1) PQ(t2, 2) PQ(t3, 3)
#undef PQ
    }

    // ---- phase 3: softmax over s.  weight ∝ exp(-2*(t - tmin)) ----
    float tq[4] = {t0.x + t0.y, t1.x + t1.y, t2.x + t2.y, t3.x + t3.y};
    #pragma unroll
    for (int q = 0; q < 4; ++q) {
        float m = tq[q];
        #pragma unroll
        for (int o = 32; o > 0; o >>= 1) m = fminf(m, __shfl_down(m, o));
        if (lane == 0) red[0][q][wid] = m;
    }
    __syncthreads();
    float M[4];
    #pragma unroll
    for (int q = 0; q < 4; ++q) {
        float m = red[0][q][0];
        #pragma unroll
        for (int i = 1; i < 16; ++i) m = fminf(m, red[0][q][i]);
        M[q] = m;
    }
    float e[4];
    #pragma unroll
    for (int q = 0; q < 4; ++q) {
        e[q] = __builtin_amdgcn_exp2f((M[q] - tq[q]) * KSC);   // exp(-2(t-tmin))
        float sum = e[q];
        #pragma unroll
        for (int o = 32; o > 0; o >>= 1) sum += __shfl_down(sum, o);
        if (lane == 0) red[1][q][wid] = sum;
    }
    __syncthreads();
    float* __restrict__ outw = out + (size_t)NB * NSQ * HIN;   // weights at 262144
    float wgt[4];
    #pragma unroll
    for (int q = 0; q < 4; ++q) {
        float d = red[1][q][0];
        #pragma unroll
        for (int i = 1; i < 16; ++i) d += red[1][q][i];
        wgt[q] = e[q] * __builtin_amdgcn_rcpf(d);
        outw[(size_t)(bq0 + q) * SKV + tid] = wgt[q];          // coalesced per q
    }
    *(float4*)&wt_s[tid][0] = make_float4(wgt[0], wgt[1], wgt[2], wgt[3]);
    __syncthreads();

    // ---- phase 4: out[q][h] = sum_s w[q][s]*kv[b][s][h], packed FMA ----
    {
        const int g = wid;                 // 0..15, s in [g*64, g*64+64)
        f32x2 a0l={0,0},a0h={0,0},a1l={0,0},a1h={0,0};
        f32x2 a2l={0,0},a2h={0,0},a3l={0,0},a3h={0,0};
        const float4* __restrict__ kvb =
            (const float4*)kv + (size_t)(b * SKV + g * 64) * 64;
        #pragma unroll 4
        for (int i = 0; i < 64; ++i) {
            const float4 w4 = *((const float4*)&wt_s[g * 64 + i][0]); // broadcast
            const float4 v  = kvb[(size_t)i * 64 + lane];             // 1KB/wave
            const f32x2 vl = {v.x, v.y}, vh = {v.z, v.w};
            a0l = __builtin_elementwise_fma((f32x2){w4.x, w4.x}, vl, a0l);
            a0h = __builtin_elementwise_fma((f32x2){w4.x, w4.x}, vh, a0h);
            a1l = __builtin_elementwise_fma((f32x2){w4.y, w4.y}, vl, a1l);
            a1h = __builtin_elementwise_fma((f32x2){w4.y, w4.y}, vh, a1h);
            a2l = __builtin_elementwise_fma((f32x2){w4.z, w4.z}, vl, a2l);
            a2h = __builtin_elementwise_fma((f32x2){w4.z, w4.z}, vh, a2h);
            a3l = __builtin_elementwise_fma((f32x2){w4.w, w4.w}, vl, a3l);
            a3h = __builtin_elementwise_fma((f32x2){w4.w, w4.w}, vh, a3h);
        }
        ((float4*)part[g][0])[lane] = make_float4(a0l.x, a0l.y, a0h.x, a0h.y);
        ((float4*)part[g][1])[lane] = make_float4(a1l.x, a1l.y, a1h.x, a1h.y);
        ((float4*)part[g][2])[lane] = make_float4(a2l.x, a2l.y, a2h.x, a2h.y);
        ((float4*)part[g][3])[lane] = make_float4(a3l.x, a3l.y, a3h.x, a3h.y);
    }
    __syncthreads();
    {
        const int q = tid >> 8, h = tid & 255;       // 1024 outputs, 1/thread
        float v = 0.f;
        #pragma unroll
        for (int g2 = 0; g2 < 16; ++g2) v += part[g2][q][h];   // stride-1 banks
        out[(size_t)(bq0 + q) * HIN + h] = v;        // coalesced
    }
}

extern "C" void kernel_launch(void* const* d_in, const int* in_sizes, int n_in,
                              void* d_out, int out_size, void* d_ws, size_t ws_size,
                              hipStream_t stream) {
    (void)in_sizes; (void)n_in; (void)out_size; (void)ws_size;
    const float* kv  = (const float*)d_in[0];
    const float* qy  = (const float*)d_in[1];
    const float* Wkv = (const float*)d_in[2];
    const float* bkv = (const float*)d_in[3];
    const float* Wq  = (const float*)d_in[4];
    const float* bqv = (const float*)d_in[5];
    const float* wv  = (const float*)d_in[6];
    float*    ekT   = (float*)d_ws;                          // 1 MB
    unsigned* slots = (unsigned*)((char*)d_ws + (1 << 20));  // 256 slots @ +1 MB
    float* out = (float*)d_out;

    hipLaunchKernelGGL(fused_kernel, dim3(NB * NSQ / 4), dim3(1024), 0, stream,
                       kv, qy, Wkv, bkv, Wq, bqv, wv, ekT, slots, out);
}

// Round 10
// 140.377 us; speedup vs baseline: 1.0324x; 1.0131x over previous
//
#include <hip/hip_runtime.h>

#define NB   2
#define SKV  1024
#define NSQ  512
#define HIN  256
#define HA   128

// projections pre-scaled by 2*log2(e):  exp2(KSC*x) = e^{2x}
// tanh(x) = 1 - 2/(e^{2x}+1); softmax is shift-invariant so the constant
// W0+bv terms of the score are dropped entirely.
#define KSC   2.8853900817779268f   // 2*log2(e)
#define MAGIC 0x1B7F3A29u           // barrier token (never a poison pattern)

// ---------------- single fused kernel, NORMAL launch ----------------
// grid 256 x 1024, 97 KB LDS -> exactly 1 block/CU, all 256 co-resident.
// stage A: block bid projects kv rows [bid*8,bid*8+8) -> ekT (global) and its
//          own 4 q rows -> eq_s (LDS only).
// software device barrier: ONE release fence + relaxed store; relaxed polling
// (coherent, NO per-poll cache invalidate); ONE acquire fence after.
// stage B: R6/R8's measured-best fused attn (scores + softmax + weights + out).
__global__ __launch_bounds__(1024) void fused_kernel(
    const float* __restrict__ kv,          // (2048,256)
    const float* __restrict__ qy,          // (1024,256)
    const float* __restrict__ Wkv,         // (256,128)
    const float* __restrict__ bkv,         // (128)
    const float* __restrict__ Wq,          // (256,128)
    const float* __restrict__ bqv,         // (128)
    const float* __restrict__ wv,          // (128)
    float* __restrict__ ekT,               // ws: (b,32,1024,4) interleaved exps
    unsigned* __restrict__ slots,          // ws: 256 barrier slots
    float* __restrict__ out)               // [262144 out0][1048576 weights]
{
    __shared__ __align__(16) float rowf[8][HIN];       // 8 KB kv-row stage
    __shared__ __align__(16) float qrow[4][HIN];       // 4 KB q-row stage
    __shared__ __align__(16) float eq_s[4][HA];        // 2 KB
    __shared__ __align__(16) float wv_s[HA];           // 0.5 KB
    __shared__ __align__(16) float wt_s[SKV][4];       // 16 KB
    __shared__ __align__(16) float part[16][4][HIN];   // 64 KB
    __shared__ float red[2][4][16];

    const int tid  = threadIdx.x;
    const int lane = tid & 63, wid = tid >> 6;
    const int bid  = blockIdx.x;
    const int bq0  = bid * 4;              // this block's 4 q rows
    const int b    = bq0 >> 9;

    // ---- stage A load: 8 kv rows + 4 qy rows + wv ----
    {
        const float4* __restrict__ kvsrc = (const float4*)(kv + (size_t)bid * 8 * HIN);
        const float4* __restrict__ qsrc  = (const float4*)(qy + (size_t)bq0 * HIN);
        if (tid < 512)      ((float4*)rowf)[tid]       = kvsrc[tid];
        else if (tid < 768) ((float4*)qrow)[tid - 512] = qsrc[tid - 512];
        else if (tid < 896) wv_s[tid - 768]            = wv[tid - 768];
    }
    __syncthreads();

    // ---- stage A project: slots 0-3 -> kv row pairs, 4-5 -> q row pairs ----
    {
        const int a = tid & 127, slot = tid >> 7;      // slot wave-uniform
        if (slot < 6) {
            const bool isq = (slot >= 4);
            const int  ra  = isq ? (slot - 4) * 2 : slot * 2;
            const float4* __restrict__ r0p =
                (const float4*)(isq ? qrow[ra] : rowf[ra]);
            const float4* __restrict__ r1p =
                (const float4*)(isq ? qrow[ra + 1] : rowf[ra + 1]);
            const float* __restrict__ W  = isq ? Wq  : Wkv;
            const float* __restrict__ bs = isq ? bqv : bkv;

            float a0 = 0.f, a1 = 0.f;
            #pragma unroll 4
            for (int h4 = 0; h4 < 64; ++h4) {
                const float4 rA = r0p[h4];             // LDS broadcast b128
                const float4 rB = r1p[h4];
                #pragma unroll
                for (int j = 0; j < 4; ++j) {
                    const float w = W[(size_t)(h4 * 4 + j) * HA + a];  // coalesced
                    a0 = fmaf(((const float*)&rA)[j], w, a0);
                    a1 = fmaf(((const float*)&rB)[j], w, a1);
                }
            }
            const float bb = bs[a];
            const float e0 = __builtin_amdgcn_exp2f((a0 + bb) * KSC);
            const float e1 = __builtin_amdgcn_exp2f((a1 + bb) * KSC);
            if (isq) {
                eq_s[ra][a]     = e0;                  // block-local, LDS only
                eq_s[ra + 1][a] = e1;
            } else {
                const int kr0 = bid * 8;               // global kv row base
                const int bI = kr0 >> 10, s0 = kr0 & 1023;
                float* __restrict__ p =
                    ekT + ((size_t)(bI * 32 + (a >> 2)) * SKV + s0) * 4 + (a & 3);
                p[(size_t)ra * 4]       = e0;
                p[(size_t)(ra + 1) * 4] = e1;
            }
        }
    }
    __syncthreads();

    // ---- software device barrier (relaxed poll; fences only at edges) ----
    if (tid == 0) {
        __builtin_amdgcn_fence(__ATOMIC_RELEASE, "agent");     // ekT visible
        __hip_atomic_store(&slots[bid], MAGIC, __ATOMIC_RELAXED,
                           __HIP_MEMORY_SCOPE_AGENT);
    }
    if (wid == 0) {                        // wave 0 polls all 256 slots
        #pragma unroll
        for (int k = 0; k < 4; ++k) {
            const int i = lane * 4 + k;
            int guard = 0;
            while (__hip_atomic_load(&slots[i], __ATOMIC_RELAXED,
                                     __HIP_MEMORY_SCOPE_AGENT) != MAGIC) {
                if (++guard > (1 << 22)) break;        // safety valve
                __builtin_amdgcn_s_sleep(1);
            }
        }
    }
    __syncthreads();
    __builtin_amdgcn_fence(__ATOMIC_ACQUIRE, "agent");         // before ekT reads

    // ---- phase 2: per-thread s, 4 q accumulators; paired rcp over a ----
    const float4* __restrict__ E4 =
        (const float4*)ekT + (size_t)b * 32 * SKV + tid;   // + a4*SKV per iter
    float t0 = 0.f, t1 = 0.f, t2 = 0.f, t3 = 0.f;

    #pragma unroll 4
    for (int a4 = 0; a4 < 32; ++a4) {
        const float4 E = E4[(size_t)a4 * SKV];             // coalesced b128
        const float4 w = ((const float4*)wv_s)[a4];        // LDS broadcast

#define PQ(ACC, QI)                                                           \
        {                                                                     \
            const float4 Q = ((const float4*)eq_s[QI])[a4];  /* broadcast */  \
            float u  = fmaf(E.x, Q.x, 1.f);                                   \
            float v  = fmaf(E.y, Q.y, 1.f);                                   \
            ACC = fmaf(fmaf(w.x, v, w.y * u),                                 \
                       __builtin_amdgcn_rcpf(u * v), ACC);                    \
            float u2 = fmaf(E.z, Q.z, 1.f);                                   \
            float v2 = fmaf(E.w, Q.w, 1.f);                                   \
            ACC = fmaf(fmaf(w.z, v2, w.w * u2),                               \
                       __builtin_amdgcn_rcpf(u2 * v2), ACC);                  \
        }
        PQ(t0, 0) PQ(t1, 1) PQ(t2, 2) PQ(t3, 3)
#undef PQ
    }

    // ---- phase 3: softmax over s.  weight ∝ exp(-2*(t - tmin)) ----
    float tq[4] = {t0, t1, t2, t3};
    #pragma unroll
    for (int q = 0; q < 4; ++q) {
        float m = tq[q];
        #pragma unroll
        for (int o = 32; o > 0; o >>= 1) m = fminf(m, __shfl_down(m, o));
        if (lane == 0) red[0][q][wid] = m;
    }
    __syncthreads();
    float M[4];
    #pragma unroll
    for (int q = 0; q < 4; ++q) {
        float m = red[0][q][0];
        #pragma unroll
        for (int i = 1; i < 16; ++i) m = fminf(m, red[0][q][i]);
        M[q] = m;
    }
    float e[4];
    #pragma unroll
    for (int q = 0; q < 4; ++q) {
        e[q] = __builtin_amdgcn_exp2f((M[q] - tq[q]) * KSC);   // exp(-2(t-tmin))
        float sum = e[q];
        #pragma unroll
        for (int o = 32; o > 0; o >>= 1) sum += __shfl_down(sum, o);
        if (lane == 0) red[1][q][wid] = sum;
    }
    __syncthreads();
    float* __restrict__ outw = out + (size_t)NB * NSQ * HIN;   // weights at 262144
    float wgt[4];
    #pragma unroll
    for (int q = 0; q < 4; ++q) {
        float d = red[1][q][0];
        #pragma unroll
        for (int i = 1; i < 16; ++i) d += red[1][q][i];
        wgt[q] = e[q] * __builtin_amdgcn_rcpf(d);
        outw[(size_t)(bq0 + q) * SKV + tid] = wgt[q];          // coalesced per q
    }
    *(float4*)&wt_s[tid][0] = make_float4(wgt[0], wgt[1], wgt[2], wgt[3]);
    __syncthreads();

    // ---- phase 4: out[q][h] = sum_s w[q][s]*kv[b][s][h] ----
    {
        const int g = wid;                 // 0..15, s in [g*64, g*64+64)
        float4 ac0 = {0,0,0,0}, ac1 = {0,0,0,0}, ac2 = {0,0,0,0}, ac3 = {0,0,0,0};
        const float4* __restrict__ kvb =
            (const float4*)kv + (size_t)(b * SKV + g * 64) * 64;
        #pragma unroll 4
        for (int i = 0; i < 64; ++i) {
            const float4 w4 = *((const float4*)&wt_s[g * 64 + i][0]); // broadcast
            const float4 v  = kvb[(size_t)i * 64 + lane];             // 1KB/wave
            ac0.x = fmaf(w4.x, v.x, ac0.x); ac0.y = fmaf(w4.x, v.y, ac0.y);
            ac0.z = fmaf(w4.x, v.z, ac0.z); ac0.w = fmaf(w4.x, v.w, ac0.w);
            ac1.x = fmaf(w4.y, v.x, ac1.x); ac1.y = fmaf(w4.y, v.y, ac1.y);
            ac1.z = fmaf(w4.y, v.z, ac1.z); ac1.w = fmaf(w4.y, v.w, ac1.w);
            ac2.x = fmaf(w4.z, v.x, ac2.x); ac2.y = fmaf(w4.z, v.y, ac2.y);
            ac2.z = fmaf(w4.z, v.z, ac2.z); ac2.w = fmaf(w4.z, v.w, ac2.w);
            ac3.x = fmaf(w4.w, v.x, ac3.x); ac3.y = fmaf(w4.w, v.y, ac3.y);
            ac3.z = fmaf(w4.w, v.z, ac3.z); ac3.w = fmaf(w4.w, v.w, ac3.w);
        }
        ((float4*)part[g][0])[lane] = ac0;
        ((float4*)part[g][1])[lane] = ac1;
        ((float4*)part[g][2])[lane] = ac2;
        ((float4*)part[g][3])[lane] = ac3;
    }
    __syncthreads();
    {
        const int q = tid >> 8, h = tid & 255;       // 1024 outputs, 1/thread
        float v = 0.f;
        #pragma unroll
        for (int g2 = 0; g2 < 16; ++g2) v += part[g2][q][h];   // stride-1 banks
        out[(size_t)(bq0 + q) * HIN + h] = v;        // coalesced
    }
}

extern "C" void kernel_launch(void* const* d_in, const int* in_sizes, int n_in,
                              void* d_out, int out_size, void* d_ws, size_t ws_size,
                              hipStream_t stream) {
    (void)in_sizes; (void)n_in; (void)out_size; (void)ws_size;
    const float* kv  = (const float*)d_in[0];
    const float* qy  = (const float*)d_in[1];
    const float* Wkv = (const float*)d_in[2];
    const float* bkv = (const float*)d_in[3];
    const float* Wq  = (const float*)d_in[4];
    const float* bqv = (const float*)d_in[5];
    const float* wv  = (const float*)d_in[6];
    float*    ekT   = (float*)d_ws;                          // 1 MB
    unsigned* slots = (unsigned*)((char*)d_ws + (1 << 20));  // 256 slots @ +1 MB
    float* out = (float*)d_out;

    hipLaunchKernelGGL(fused_kernel, dim3(NB * NSQ / 4), dim3(1024), 0, stream,
                       kv, qy, Wkv, bkv, Wq, bqv, wv, ekT, slots, out);
}

// Round 11
// 111.398 us; speedup vs baseline: 1.3010x; 1.2601x over previous
//
#include <hip/hip_runtime.h>

#define NB   2
#define SKV  1024
#define NSQ  512
#define HIN  256
#define HA   128

// projections pre-scaled by 2*log2(e):  exp2(KSC*x) = e^{2x}
// tanh(x) = 1 - 2/(e^{2x}+1); softmax is shift-invariant so the constant
// W0+bv terms of the score are dropped entirely.
#define KSC   2.8853900817779268f   // 2*log2(e)

// ---------------- Kernel A: projections -> exponentials ----------------
// (R2/R6 version, unchanged — part of the best measured build.)
// kv rows -> ekT, INTERLEAVED-TRANSPOSED: ekT[b][a>>2][s][a&3]; q rows -> eq
// row-major [r][a].
__global__ __launch_bounds__(512) void proj_kernel(
    const float* __restrict__ kv,
    const float* __restrict__ qy,
    const float* __restrict__ Wkv,
    const float* __restrict__ bkv,
    const float* __restrict__ Wq,
    const float* __restrict__ bq,
    float* __restrict__ ekT,
    float* __restrict__ eq)
{
    __shared__ __align__(16) float rowf[8][HIN];
    const int t  = threadIdx.x;
    const int a  = t & 127;            // output channel
    const int rh = t >> 7;             // row-pair id (0..3)
    const int r0 = blockIdx.x * 8;     // 8 rows per block
    const bool is_q = (r0 >= NB * SKV);
    const float* __restrict__ src = is_q ? (qy + (size_t)(r0 - NB * SKV) * HIN)
                                         : (kv + (size_t)r0 * HIN);
    const float* __restrict__ W  = is_q ? Wq : Wkv;
    const float* __restrict__ bs = is_q ? bq : bkv;

    ((float4*)rowf)[t] = ((const float4*)src)[t];
    __syncthreads();

    float a0 = 0.f, a1 = 0.f;
    const int ra = rh * 2, rb = rh * 2 + 1;
    #pragma unroll 4
    for (int h4 = 0; h4 < 64; ++h4) {
        const float4 r4a = ((const float4*)rowf[ra])[h4];
        const float4 r4b = ((const float4*)rowf[rb])[h4];
        #pragma unroll
        for (int j = 0; j < 4; ++j) {
            const float w = W[(size_t)(h4 * 4 + j) * HA + a];
            a0 = fmaf(((const float*)&r4a)[j], w, a0);
            a1 = fmaf(((const float*)&r4b)[j], w, a1);
        }
    }
    const float bb = bs[a];
    const float e0 = __builtin_amdgcn_exp2f((a0 + bb) * KSC);
    const float e1 = __builtin_amdgcn_exp2f((a1 + bb) * KSC);
    if (is_q) {
        const int r = r0 - NB * SKV;
        eq[(size_t)(r + ra) * HA + a] = e0;
        eq[(size_t)(r + rb) * HA + a] = e1;
    } else {
        const int bI = r0 >> 10, s0 = r0 & 1023;
        float* __restrict__ p =
            ekT + ((size_t)(bI * 32 + (a >> 2)) * SKV + s0) * 4 + (a & 3);
        p[(size_t)ra * 4] = e0;
        p[(size_t)rb * 4] = e1;
    }
}

// ---------------- Kernel B: scores + softmax + weights + output (FUSED) ----
// one block = 4 (b,q) rows; 512 threads (8 waves); grid 256 (1 block/CU).
// Each thread owns TWO s rows (s = tid, tid+512): the 5 LDS-broadcast b128
// reads per a4 (wv + 4 Q) are amortized over 2 s -> per-CU phase-2 LDS
// return-bandwidth HALVES vs the 1024-thread version; kv traffic unchanged
// (q=4 per block, grid 256 — R7's doubling mistake avoided).
__global__ __launch_bounds__(512) void attn_kernel(
    const float* __restrict__ ekT,         // (b,32,1024,4) interleaved exps
    const float* __restrict__ eq,          // (1024,128) exps, row-major
    const float* __restrict__ wv,          // (128)
    const float* __restrict__ kv,          // (2048,256) f32
    float* __restrict__ out)               // [262144 out0][1048576 weights]
{
    __shared__ __align__(16) float eq_s[4][HA];        // 2 KB
    __shared__ __align__(16) float wv_s[HA];           // 0.5 KB
    __shared__ __align__(16) float wt_s[SKV][4];       // 16 KB
    __shared__ __align__(16) float part[8][4][HIN];    // 32 KB
    __shared__ float red[2][4][8];

    const int tid  = threadIdx.x;
    const int lane = tid & 63, wid = tid >> 6;         // 8 waves
    const int bq0  = blockIdx.x * 4;       // never straddles b (512%4==0)
    const int b    = bq0 >> 9;

    ((float*)eq_s)[tid & 511] = eq[(size_t)bq0 * HA + (tid & 511)];
    if (tid < HA) wv_s[tid] = wv[tid];
    __syncthreads();

    // ---- phase 2: 2 s per thread, 4 q accumulators; paired rcp over a ----
    const float4* __restrict__ E4 =
        (const float4*)ekT + (size_t)b * 32 * SKV;
    float t0a = 0.f, t1a = 0.f, t2a = 0.f, t3a = 0.f;  // s = tid
    float t0b = 0.f, t1b = 0.f, t2b = 0.f, t3b = 0.f;  // s = tid + 512

    #pragma unroll 4
    for (int a4 = 0; a4 < 32; ++a4) {
        const float4 Ea = E4[(size_t)a4 * SKV + tid];        // coalesced b128
        const float4 Eb = E4[(size_t)a4 * SKV + tid + 512];  // coalesced b128
        const float4 w  = ((const float4*)wv_s)[a4];         // LDS broadcast

#define PQ(ACC, E, QI)                                                        \
        {                                                                     \
            const float4 Q = ((const float4*)eq_s[QI])[a4];  /* broadcast */  \
            float u  = fmaf(E.x, Q.x, 1.f);                                   \
            float v  = fmaf(E.y, Q.y, 1.f);                                   \
            ACC = fmaf(fmaf(w.x, v, w.y * u),                                 \
                       __builtin_amdgcn_rcpf(u * v), ACC);                    \
            float u2 = fmaf(E.z, Q.z, 1.f);                                   \
            float v2 = fmaf(E.w, Q.w, 1.f);                                   \
            ACC = fmaf(fmaf(w.z, v2, w.w * u2),                               \
                       __builtin_amdgcn_rcpf(u2 * v2), ACC);                  \
        }
        PQ(t0a, Ea, 0) PQ(t1a, Ea, 1) PQ(t2a, Ea, 2) PQ(t3a, Ea, 3)
        PQ(t0b, Eb, 0) PQ(t1b, Eb, 1) PQ(t2b, Eb, 2) PQ(t3b, Eb, 3)
#undef PQ
    }

    // ---- phase 3: softmax over s.  weight ∝ exp(-2*(t - tmin)) ----
    float tq[4][2] = {{t0a, t0b}, {t1a, t1b}, {t2a, t2b}, {t3a, t3b}};
    #pragma unroll
    for (int q = 0; q < 4; ++q) {
        float m = fminf(tq[q][0], tq[q][1]);
        #pragma unroll
        for (int o = 32; o > 0; o >>= 1) m = fminf(m, __shfl_down(m, o));
        if (lane == 0) red[0][q][wid] = m;
    }
    __syncthreads();
    float M[4];
    #pragma unroll
    for (int q = 0; q < 4; ++q) {
        float m = red[0][q][0];
        #pragma unroll
        for (int i = 1; i < 8; ++i) m = fminf(m, red[0][q][i]);
        M[q] = m;
    }
    float e[4][2];
    #pragma unroll
    for (int q = 0; q < 4; ++q) {
        e[q][0] = __builtin_amdgcn_exp2f((M[q] - tq[q][0]) * KSC);
        e[q][1] = __builtin_amdgcn_exp2f((M[q] - tq[q][1]) * KSC);
        float sum = e[q][0] + e[q][1];
        #pragma unroll
        for (int o = 32; o > 0; o >>= 1) sum += __shfl_down(sum, o);
        if (lane == 0) red[1][q][wid] = sum;
    }
    __syncthreads();
    float* __restrict__ outw = out + (size_t)NB * NSQ * HIN;   // weights at 262144
    float rw[4];
    #pragma unroll
    for (int q = 0; q < 4; ++q) {
        float d = red[1][q][0];
        #pragma unroll
        for (int i = 1; i < 8; ++i) d += red[1][q][i];
        rw[q] = __builtin_amdgcn_rcpf(d);
    }
    #pragma unroll
    for (int si = 0; si < 2; ++si) {
        const int s = si * 512 + tid;
        float wq[4];
        #pragma unroll
        for (int q = 0; q < 4; ++q) {
            wq[q] = e[q][si] * rw[q];
            outw[(size_t)(bq0 + q) * SKV + s] = wq[q];         // coalesced per q
        }
        *(float4*)&wt_s[s][0] = make_float4(wq[0], wq[1], wq[2], wq[3]);
    }
    __syncthreads();

    // ---- phase 4: out[q][h] = sum_s w[q][s]*kv[b][s][h] ----
    // wave g handles s in [g*128, g*128+128); lane = float4 chunk of h
    {
        const int g = wid;                 // 0..7
        float4 ac0 = {0,0,0,0}, ac1 = {0,0,0,0}, ac2 = {0,0,0,0}, ac3 = {0,0,0,0};
        const float4* __restrict__ kvb =
            (const float4*)kv + (size_t)(b * SKV + g * 128) * 64;
        #pragma unroll 4
        for (int i = 0; i < 128; ++i) {
            const float4 w4 = *((const float4*)&wt_s[g * 128 + i][0]); // broadcast
            const float4 v  = kvb[(size_t)i * 64 + lane];              // 1KB/wave
            ac0.x = fmaf(w4.x, v.x, ac0.x); ac0.y = fmaf(w4.x, v.y, ac0.y);
            ac0.z = fmaf(w4.x, v.z, ac0.z); ac0.w = fmaf(w4.x, v.w, ac0.w);
            ac1.x = fmaf(w4.y, v.x, ac1.x); ac1.y = fmaf(w4.y, v.y, ac1.y);
            ac1.z = fmaf(w4.y, v.z, ac1.z); ac1.w = fmaf(w4.y, v.w, ac1.w);
            ac2.x = fmaf(w4.z, v.x, ac2.x); ac2.y = fmaf(w4.z, v.y, ac2.y);
            ac2.z = fmaf(w4.z, v.z, ac2.z); ac2.w = fmaf(w4.z, v.w, ac2.w);
            ac3.x = fmaf(w4.w, v.x, ac3.x); ac3.y = fmaf(w4.w, v.y, ac3.y);
            ac3.z = fmaf(w4.w, v.z, ac3.z); ac3.w = fmaf(w4.w, v.w, ac3.w);
        }
        ((float4*)part[g][0])[lane] = ac0;
        ((float4*)part[g][1])[lane] = ac1;
        ((float4*)part[g][2])[lane] = ac2;
        ((float4*)part[g][3])[lane] = ac3;
    }
    __syncthreads();
    #pragma unroll
    for (int k = 0; k < 2; ++k) {
        const int id = k * 512 + tid;
        const int q = id >> 8, h = id & 255;         // 1024 outputs, 2/thread
        float v = 0.f;
        #pragma unroll
        for (int g2 = 0; g2 < 8; ++g2) v += part[g2][q][h];    // stride-1 banks
        out[(size_t)(bq0 + q) * HIN + h] = v;        // coalesced
    }
}

extern "C" void kernel_launch(void* const* d_in, const int* in_sizes, int n_in,
                              void* d_out, int out_size, void* d_ws, size_t ws_size,
                              hipStream_t stream) {
    (void)in_sizes; (void)n_in; (void)out_size; (void)ws_size;
    const float* kv  = (const float*)d_in[0];
    const float* qy  = (const float*)d_in[1];
    const float* Wkv = (const float*)d_in[2];
    const float* bkv = (const float*)d_in[3];
    const float* Wq  = (const float*)d_in[4];
    const float* bq  = (const float*)d_in[5];
    const float* wv  = (const float*)d_in[6];
    float* ekT = (float*)d_ws;                 // 1 MB
    float* eqp = ekT + (size_t)NB * SKV * HA;  // 0.5 MB
    float* out = (float*)d_out;

    hipLaunchKernelGGL(proj_kernel, dim3((NB * SKV + NB * NSQ) / 8), dim3(512), 0, stream,
                       kv, qy, Wkv, bkv, Wq, bq, ekT, eqp);
    hipLaunchKernelGGL(attn_kernel, dim3(NB * NSQ / 4), dim3(512), 0, stream,
                       ekT, eqp, wv, kv, out);
}